// Round 2
// baseline (197.234 us; speedup 1.0000x reference)
//
#include <hip/hip_runtime.h>

// Capsule routing: B=256, J=2, N=6912, E=16, D=8, 2 routing iters. All fp32.
// R12: R11 was latency-bound: grid 768 = 3 blocks/CU (Occupancy 22%), VALUBusy
// 38-62%, and SQ_LDS_BANK_CONFLICT = 4.0x ds_read count (e*32B stride -> 4-way).
// Fixes: (1) XOR-swizzle W tile in 16B units (u ^= u>>3 within 128-float row)
// -> 2-way max (free); read offsets sA/sB are lane constants, zero loop cost.
// (2) n-split CGX=256/NB=27 -> 1024 blocks = exactly 4/CU (27KB LDS), partial
// 8.4MB (ws-gated, tiered fallback to 192/36 then kmono). (3) ping-pong
// unroll-2 x prefetch (no per-iter register copies).
#define B_ 256
#define J_ 2
#define N_ 6912
#define E_ 16
#define D_ 8
#define BSTR (4*N_*D_)   // float stride between a thread's consecutive b's (4 rows)

// sum over the 16-lane row (e-lanes sharing b_lo), pure VALU/DPP:
__device__ __forceinline__ float dpp_row_add16(float v){
  v += __int_as_float(__builtin_amdgcn_update_dpp(0, __float_as_int(v), 0xB1,  0xF, 0xF, true)); // quad_perm [1,0,3,2]  : xor 1
  v += __int_as_float(__builtin_amdgcn_update_dpp(0, __float_as_int(v), 0x4E,  0xF, 0xF, true)); // quad_perm [2,3,0,1]  : xor 2
  v += __int_as_float(__builtin_amdgcn_update_dpp(0, __float_as_int(v), 0x141, 0xF, 0xF, true)); // row_half_mirror      : xor 7
  v += __int_as_float(__builtin_amdgcn_update_dpp(0, __float_as_int(v), 0x140, 0xF, 0xF, true)); // row_mirror           : xor 15
  return v;
}

__device__ __forceinline__ void ldx(const float* __restrict__ xp, int ni,
                                    float4 (&xa)[4], float4 (&xb)[4]){
  #pragma unroll
  for (int k=0;k<4;++k){
    xa[k] = *(const float4*)(xp + (size_t)k*BSTR + ni*8);
    xb[k] = *(const float4*)(xp + (size_t)k*BSTR + ni*8 + 4);
  }
}

template<int NBT>
__device__ __forceinline__ void body1(const float4* __restrict__ smem4, int ni,
                                      int sA, int sB,
                                      const float4 (&xa)[4], const float4 (&xb)[4],
                                      float (&acc0)[4], float (&acc1)[4]){
  const float4 wa0 = smem4[ni*32 + sA];
  const float4 wb0 = smem4[ni*32 + sB];
  const float4 wa1 = smem4[(NBT + ni)*32 + sA];
  const float4 wb1 = smem4[(NBT + ni)*32 + sB];
  #pragma unroll
  for (int k=0;k<4;++k){
    float a0 = acc0[k], a1 = acc1[k];
    a0 = fmaf(wa0.x, xa[k].x, a0); a0 = fmaf(wa0.y, xa[k].y, a0);
    a0 = fmaf(wa0.z, xa[k].z, a0); a0 = fmaf(wa0.w, xa[k].w, a0);
    a0 = fmaf(wb0.x, xb[k].x, a0); a0 = fmaf(wb0.y, xb[k].y, a0);
    a0 = fmaf(wb0.z, xb[k].z, a0); a0 = fmaf(wb0.w, xb[k].w, a0);
    a1 = fmaf(wa1.x, xa[k].x, a1); a1 = fmaf(wa1.y, xa[k].y, a1);
    a1 = fmaf(wa1.z, xa[k].z, a1); a1 = fmaf(wa1.w, xa[k].w, a1);
    a1 = fmaf(wb1.x, xb[k].x, a1); a1 = fmaf(wb1.y, xb[k].y, a1);
    a1 = fmaf(wb1.z, xb[k].z, a1); a1 = fmaf(wb1.w, xb[k].w, a1);
    acc0[k] = a0; acc1[k] = a1;
  }
}

template<int NBT>
__device__ __forceinline__ void body2(const float4* __restrict__ smem4, int ni,
                                      int sA, int sB,
                                      const float4 (&xa)[4], const float4 (&xb)[4],
                                      const float (&vj0)[4], const float (&vj1)[4],
                                      float (&acc0)[4], float (&acc1)[4]){
  const float4 wa0 = smem4[ni*32 + sA];
  const float4 wb0 = smem4[ni*32 + sB];
  const float4 wa1 = smem4[(NBT + ni)*32 + sA];
  const float4 wb1 = smem4[(NBT + ni)*32 + sB];
  float u0[4], u1[4];
  #pragma unroll
  for (int k=0;k<4;++k){
    float a0, a1;
    a0 = wa0.x*xa[k].x;            a0 = fmaf(wa0.y, xa[k].y, a0);
    a0 = fmaf(wa0.z, xa[k].z, a0); a0 = fmaf(wa0.w, xa[k].w, a0);
    a0 = fmaf(wb0.x, xb[k].x, a0); a0 = fmaf(wb0.y, xb[k].y, a0);
    a0 = fmaf(wb0.z, xb[k].z, a0); a0 = fmaf(wb0.w, xb[k].w, a0);
    a1 = wa1.x*xa[k].x;            a1 = fmaf(wa1.y, xa[k].y, a1);
    a1 = fmaf(wa1.z, xa[k].z, a1); a1 = fmaf(wa1.w, xa[k].w, a1);
    a1 = fmaf(wb1.x, xb[k].x, a1); a1 = fmaf(wb1.y, xb[k].y, a1);
    a1 = fmaf(wb1.z, xb[k].z, a1); a1 = fmaf(wb1.w, xb[k].w, a1);
    u0[k] = a0; u1[k] = a1;
  }
  #pragma unroll
  for (int k=0;k<4;++k){
    const float d  = dpp_row_add16(fmaf(vj1[k], u1[k], -(vj0[k]*u0[k])));
    const float c0 = __builtin_amdgcn_rcpf(1.f + __expf(d));   // softmax over 2 caps
    acc0[k] = fmaf(c0,       u0[k], acc0[k]);
    acc1[k] = fmaf(1.f - c0, u1[k], acc1[k]);
  }
}

// stage W[j][NBT n][16 e][8 d] -> LDS, XOR-swizzled in 16B units within each
// 128-float row: unit' = unit ^ (unit>>3). Writes stay conflict-free; reads
// (e*32B stride) become 2-way (free) instead of 4-way.
template<int NBT>
__device__ __forceinline__ void stageW(const float* __restrict__ W, int nb0, int tid,
                                       float4* __restrict__ smem4, float4 (&wbuf)[(J_*NBT*32 + 255)/256]){
  constexpr int TOT4 = J_*NBT*32;
  constexpr int KS = (TOT4 + 255)/256;
  #pragma unroll
  for (int k=0;k<KS;++k){
    const int idx = k*256 + tid;
    if (TOT4 % 256 == 0 || idx < TOT4){
      const int j  = (idx >= NBT*32) ? 1 : 0;
      const int r4 = idx - j*(NBT*32);
      wbuf[k] = *(const float4*)(W + ((size_t)j*N_ + nb0)*(E_*D_) + (size_t)r4*4);
    }
  }
}

template<int NBT>
__device__ __forceinline__ void writeW(int tid, float4* __restrict__ smem4,
                                       const float4 (&wbuf)[(J_*NBT*32 + 255)/256]){
  constexpr int TOT4 = J_*NBT*32;
  constexpr int KS = (TOT4 + 255)/256;
  #pragma unroll
  for (int k=0;k<KS;++k){
    const int idx = k*256 + tid;
    if (TOT4 % 256 == 0 || idx < TOT4){
      const int u = idx & 31;
      smem4[(idx & ~31) | (u ^ (u>>3))] = wbuf[k];
    }
  }
}

// ---------------- main path ----------------

template<int NBT, int MINW>
__global__ __launch_bounds__(256, MINW) void kpass1(const float* __restrict__ x,
                                                    const float* __restrict__ W,
                                                    float* __restrict__ partial)
{
  __shared__ float4 smem4[J_*NBT*32];
  const int tid  = threadIdx.x;
  const int lane = tid & 63;
  const int wv   = __builtin_amdgcn_readfirstlane(tid >> 6);
  const int e    = lane & 15;
  const int blo  = lane >> 4;
  const int nb0  = blockIdx.x * NBT;

  float4 wbuf[(J_*NBT*32 + 255)/256];
  stageW<NBT>(W, nb0, tid, smem4, wbuf);

  const int b0 = blockIdx.y*64 + wv*16 + blo;
  const float* xp = x + ((size_t)b0*N_ + nb0)*D_;
  const int sA = (e*2)   ^ ((e*2)>>3);
  const int sB = (e*2+1) ^ ((e*2+1)>>3);

  float4 xaA[4], xbA[4], xaB[4], xbB[4];
  ldx(xp, 0, xaA, xbA);
  writeW<NBT>(tid, smem4, wbuf);
  __syncthreads();

  float acc0[4] = {0,0,0,0}, acc1[4] = {0,0,0,0};
  #pragma unroll 1
  for (int ni=0; ni+1<NBT; ni+=2){
    ldx(xp, ni+1, xaB, xbB);
    body1<NBT>(smem4, ni, sA, sB, xaA, xbA, acc0, acc1);
    if (ni+2 < NBT) ldx(xp, ni+2, xaA, xbA);
    body1<NBT>(smem4, ni+1, sA, sB, xaB, xbB, acc0, acc1);
  }
  if (NBT & 1) body1<NBT>(smem4, NBT-1, sA, sB, xaA, xbA, acc0, acc1);

  float* dst = partial + (size_t)(blockIdx.x*4 + blockIdx.y)*2048
             + (wv*16 + blo)*32 + e;
  #pragma unroll
  for (int k=0;k<4;++k){
    dst[k*128]      = acc0[k];
    dst[k*128 + 16] = acc1[k];
  }
}

template<int NBT, int MINW>
__global__ __launch_bounds__(256, MINW) void kpass2(const float* __restrict__ x,
                                                    const float* __restrict__ W,
                                                    const float* __restrict__ v1,
                                                    float* __restrict__ partial)
{
  __shared__ float4 smem4[J_*NBT*32];
  const int tid  = threadIdx.x;
  const int lane = tid & 63;
  const int wv   = __builtin_amdgcn_readfirstlane(tid >> 6);
  const int e    = lane & 15;
  const int blo  = lane >> 4;
  const int nb0  = blockIdx.x * NBT;

  float4 wbuf[(J_*NBT*32 + 255)/256];
  stageW<NBT>(W, nb0, tid, smem4, wbuf);

  const int b0 = blockIdx.y*64 + wv*16 + blo;
  const float* xp = x + ((size_t)b0*N_ + nb0)*D_;
  const int sA = (e*2)   ^ ((e*2)>>3);
  const int sB = (e*2+1) ^ ((e*2+1)>>3);

  float4 xaA[4], xbA[4], xaB[4], xbB[4];
  ldx(xp, 0, xaA, xbA);
  float vj0[4], vj1[4];
  #pragma unroll
  for (int k=0;k<4;++k){
    vj0[k] = v1[(size_t)(b0 + 4*k)*32 + e];
    vj1[k] = v1[(size_t)(b0 + 4*k)*32 + 16 + e];
  }
  writeW<NBT>(tid, smem4, wbuf);
  __syncthreads();

  float acc0[4] = {0,0,0,0}, acc1[4] = {0,0,0,0};
  #pragma unroll 1
  for (int ni=0; ni+1<NBT; ni+=2){
    ldx(xp, ni+1, xaB, xbB);
    body2<NBT>(smem4, ni, sA, sB, xaA, xbA, vj0, vj1, acc0, acc1);
    if (ni+2 < NBT) ldx(xp, ni+2, xaA, xbA);
    body2<NBT>(smem4, ni+1, sA, sB, xaB, xbB, vj0, vj1, acc0, acc1);
  }
  if (NBT & 1) body2<NBT>(smem4, NBT-1, sA, sB, xaA, xbA, vj0, vj1, acc0, acc1);

  float* dst = partial + (size_t)(blockIdx.x*4 + blockIdx.y)*2048
             + (wv*16 + blo)*32 + e;
  #pragma unroll
  for (int k=0;k<4;++k){
    dst[k*128]      = acc0[k];
    dst[k*128 + 16] = acc1[k];
  }
}

// Fused reduce (sum CGXN chunk-partials) + squash (16-lane shfl butterfly).
template<bool HALF, int CGXN>
__global__ __launch_bounds__(256) void kred(const float* __restrict__ partial,
                                            float* __restrict__ dst)
{
  const int t = blockIdx.x*256 + threadIdx.x;     // grid 32 -> 8192
  const int btile = t >> 11, q = t & 2047;
  const float* p = partial + (size_t)btile*2048 + q;
  float s = 0.f;
  #pragma unroll 8
  for (int cx=0; cx<CGXN; ++cx) s += p[(size_t)cx*8192];
  if (HALF) s *= 0.5f;
  float n2 = s*s;
  #pragma unroll
  for (int m=1; m<16; m<<=1) n2 += __shfl_xor(n2, m);
  const float f = (n2/(1.f+n2)) * rsqrtf(n2 + 1e-9f);
  dst[t] = s * f;
}

// ---------------- fallback: R5 monolithic (no ws) ----------------
#define NT 512
__global__ __launch_bounds__(NT) void kmono(const float* __restrict__ x,
                                            const float* __restrict__ W,
                                            float* __restrict__ out)
{
  const int b    = blockIdx.x;
  const int tid  = threadIdx.x;
  const int wv   = tid >> 6;
  const int lane = tid & 63;
  __shared__ float wred[8*33];
  __shared__ float vsh[32];

  float acc[32];
  #pragma unroll
  for (int i=0;i<32;++i) acc[i]=0.f;
  for (int n = tid; n < N_; n += NT){
    const float4 xa = *(const float4*)(x + ((size_t)b*N_ + n)*D_);
    const float4 xb = *(const float4*)(x + ((size_t)b*N_ + n)*D_ + 4);
    #pragma unroll
    for (int j=0;j<J_;++j){
      const float* wp = W + ((size_t)j*N_ + n)*(E_*D_);
      #pragma unroll
      for (int e=0;e<E_;++e){
        const float4 wa = *(const float4*)(wp + e*8);
        const float4 wb = *(const float4*)(wp + e*8 + 4);
        float a = acc[j*16+e];
        a = fmaf(wa.x,xa.x,a); a = fmaf(wa.y,xa.y,a); a = fmaf(wa.z,xa.z,a); a = fmaf(wa.w,xa.w,a);
        a = fmaf(wb.x,xb.x,a); a = fmaf(wb.y,xb.y,a); a = fmaf(wb.z,xb.z,a); a = fmaf(wb.w,xb.w,a);
        acc[j*16+e] = a;
      }
    }
  }
  #pragma unroll
  for (int i=0;i<32;++i){
    float v = acc[i];
    #pragma unroll
    for (int off=32; off; off>>=1) v += __shfl_xor(v, off);
    acc[i] = v;
  }
  if (lane == 0){
    #pragma unroll
    for (int i=0;i<32;++i) wred[wv*33 + i] = acc[i];
  }
  __syncthreads();
  if (tid < 32){
    float s = 0.f;
    #pragma unroll
    for (int w=0;w<8;++w) s += wred[w*33 + tid];
    wred[tid] = 0.5f * s;
  }
  __syncthreads();
  if (tid < 32){
    const int j = tid >> 4; float n2 = 0.f;
    #pragma unroll
    for (int e=0;e<16;++e){ const float sv = wred[j*16+e]; n2 = fmaf(sv,sv,n2); }
    vsh[tid] = wred[tid] * (n2/(1.f+n2)) * rsqrtf(n2 + 1e-9f);
  }
  __syncthreads();
  float vv[32];
  #pragma unroll
  for (int i=0;i<32;++i) vv[i] = vsh[i];

  #pragma unroll
  for (int i=0;i<32;++i) acc[i]=0.f;
  for (int n = tid; n < N_; n += NT){
    const float4 xa = *(const float4*)(x + ((size_t)b*N_ + n)*D_);
    const float4 xb = *(const float4*)(x + ((size_t)b*N_ + n)*D_ + 4);
    float u[32];
    #pragma unroll
    for (int j=0;j<J_;++j){
      const float* wp = W + ((size_t)j*N_ + n)*(E_*D_);
      #pragma unroll
      for (int e=0;e<E_;++e){
        const float4 wa = *(const float4*)(wp + e*8);
        const float4 wb = *(const float4*)(wp + e*8 + 4);
        float a;
        a = wa.x*xa.x; a = fmaf(wa.y,xa.y,a); a = fmaf(wa.z,xa.z,a); a = fmaf(wa.w,xa.w,a);
        a = fmaf(wb.x,xb.x,a); a = fmaf(wb.y,xb.y,a); a = fmaf(wb.z,xb.z,a); a = fmaf(wb.w,xb.w,a);
        u[j*16+e] = a;
      }
    }
    float l0=0.f, l1=0.f;
    #pragma unroll
    for (int e=0;e<16;++e){ l0 = fmaf(vv[e],u[e],l0); l1 = fmaf(vv[16+e],u[16+e],l1); }
    const float c0 = 1.f/(1.f + __expf(l1 - l0));
    const float c1 = 1.f - c0;
    #pragma unroll
    for (int e=0;e<16;++e){ acc[e] = fmaf(c0,u[e],acc[e]); acc[16+e] = fmaf(c1,u[16+e],acc[16+e]); }
  }
  #pragma unroll
  for (int i=0;i<32;++i){
    float v = acc[i];
    #pragma unroll
    for (int off=32; off; off>>=1) v += __shfl_xor(v, off);
    acc[i] = v;
  }
  __syncthreads();
  if (lane == 0){
    #pragma unroll
    for (int i=0;i<32;++i) wred[wv*33 + i] = acc[i];
  }
  __syncthreads();
  if (tid < 32){
    float s = 0.f;
    #pragma unroll
    for (int w=0;w<8;++w) s += wred[w*33 + tid];
    wred[tid] = s;
  }
  __syncthreads();
  if (tid < 32){
    const int j = tid >> 4; float n2 = 0.f;
    #pragma unroll
    for (int e=0;e<16;++e){ const float sv = wred[j*16+e]; n2 = fmaf(sv,sv,n2); }
    out[(size_t)b*32 + tid] = wred[tid] * (n2/(1.f+n2)) * rsqrtf(n2 + 1e-9f);
  }
}

extern "C" void kernel_launch(void* const* d_in, const int* in_sizes, int n_in,
                              void* d_out, int out_size, void* d_ws, size_t ws_size,
                              hipStream_t stream)
{
  const float* x = (const float*)d_in[0];   // [256,6912,8]
  const float* W = (const float*)d_in[1];   // [2,6912,16,8]
  if (n_in >= 2 && in_sizes[0] < in_sizes[1]){
    x = (const float*)d_in[1]; W = (const float*)d_in[0];
  }
  float* out = (float*)d_out;               // fp32 [256,2,16]

  const size_t need_big  = (size_t)(8192 + 1024*2048) * sizeof(float);  // ~8.4 MB
  const size_t need_main = (size_t)(8192 +  768*2048) * sizeof(float);  // ~6.3 MB

  if (ws_size >= need_big){
    float* wsf     = (float*)d_ws;
    float* v1      = wsf;           // 8192 floats
    float* partial = wsf + 8192;    // 1024*2048 floats
    kpass1<27,4><<<dim3(256,4), 256, 0, stream>>>(x, W, partial);
    kred<true ,256><<<32, 256, 0, stream>>>(partial, v1);
    kpass2<27,4><<<dim3(256,4), 256, 0, stream>>>(x, W, v1, partial);
    kred<false,256><<<32, 256, 0, stream>>>(partial, out);
  } else if (ws_size >= need_main){
    float* wsf     = (float*)d_ws;
    float* v1      = wsf;
    float* partial = wsf + 8192;
    kpass1<36,3><<<dim3(192,4), 256, 0, stream>>>(x, W, partial);
    kred<true ,192><<<32, 256, 0, stream>>>(partial, v1);
    kpass2<36,3><<<dim3(192,4), 256, 0, stream>>>(x, W, v1, partial);
    kred<false,192><<<32, 256, 0, stream>>>(partial, out);
  } else {
    kmono<<<B_, NT, 0, stream>>>(x, W, out);
  }
}